// Round 1
// baseline (374.942 us; speedup 1.0000x reference)
//
#include <hip/hip_runtime.h>
#include <hip/hip_bf16.h>

typedef unsigned short ushortT;
typedef __bf16 bf16x8 __attribute__((ext_vector_type(8)));
typedef float f32x4 __attribute__((ext_vector_type(4)));

#define OUT_SCALE 0.001f

// fast GELU: v * sigmoid(1.5957691*(v + 0.044715 v^3)); |err vs exact| <~1e-3
__device__ __forceinline__ float gelu_fast(float v) {
    const float u = v * fmaf(0.044715f * v, v, 1.0f);
    const float e = __expf(-1.5957691216057308f * u);
    return v * __builtin_amdgcn_rcpf(1.0f + e);
}
__device__ __forceinline__ ushortT f2bf(float f) {
    __hip_bfloat16 h = __float2bfloat16(f);
    return *reinterpret_cast<ushortT*>(&h);
}

// ---------------------------------------------------------------------------
// K1: x path. gelu(x + dwconv3x3(x) + b) -> XgT[b][r][g2][T112][c32 swizzled]
// (chunk' = chunk ^ ((T>>1)&3)).  grid (96,64), 512 thr, thread=(c, 12-col grp).
// No input staging: each thread does 15 predicated float4 global loads (L2
// absorbs the redundancy); LDS only for the 14 KB transpose tile; ONE barrier.
// ---------------------------------------------------------------------------
__global__ __launch_bounds__(512) void k_gelu_x(
    const float* __restrict__ x, const float* __restrict__ wx,
    const float* __restrict__ bx, ushortT* __restrict__ xgt)
{
    const int r = blockIdx.x, b = blockIdx.y, tid = threadIdx.x;
    const int c = tid >> 3, colg = tid & 7, j0 = colg * 12;

    __shared__ ushortT tile[7168];  // [g2][T112][c32] swizzled

    // zero pad bands T in [0,8) and [104,112): 4 regions x 256 elems
    if (tid < 128) {
        const int region = tid >> 5, k = tid & 31;
        const int start = (region & 1) * 3328 + (region >> 1) * 3584;
        *(uint4*)(&tile[start + k * 8]) = make_uint4(0, 0, 0, 0);
    }

    float w[9];
    #pragma unroll
    for (int i = 0; i < 9; ++i) w[i] = wx[c * 9 + i];
    const float bias = bx[c];

    float acc[12], winc[12];
    #pragma unroll
    for (int jj = 0; jj < 12; ++jj) acc[jj] = bias;

    const float* xb = x + (size_t)(b * 64 + c) * 9216;
    #pragma unroll
    for (int dr = 0; dr < 3; ++dr) {
        const int rr = r + dr - 1;
        const bool rok = (rr >= 0) && (rr < 96);
        float f[20];
        #pragma unroll
        for (int m = 0; m < 5; ++m) {
            const int cs = j0 - 4 + 4 * m;
            float4 v = make_float4(0.f, 0.f, 0.f, 0.f);
            if (rok && cs >= 0 && cs <= 92)
                v = *(const float4*)(xb + rr * 96 + cs);
            f[4 * m] = v.x; f[4 * m + 1] = v.y; f[4 * m + 2] = v.z; f[4 * m + 3] = v.w;
        }
        #pragma unroll
        for (int jj = 0; jj < 12; ++jj)
            acc[jj] += f[jj + 3] * w[dr * 3] + f[jj + 4] * w[dr * 3 + 1]
                     + f[jj + 5] * w[dr * 3 + 2];
        if (dr == 1) {
            #pragma unroll
            for (int jj = 0; jj < 12; ++jj) winc[jj] = f[jj + 4];  // residual col
        }
    }

    const int g = c >> 5, cl = c & 31, chunk = cl >> 3, pos = cl & 7;
    #pragma unroll
    for (int jj = 0; jj < 12; ++jj) {
        const float gv = gelu_fast(acc[jj] + winc[jj]);
        const int T = j0 + jj + 8;
        const int schunk = chunk ^ ((T >> 1) & 3);
        tile[g * 3584 + T * 32 + schunk * 8 + pos] = f2bf(gv);
    }
    __syncthreads();

    uint4* dst = (uint4*)(xgt + (size_t)(b * 96 + r) * 7168);
    const uint4* s4 = (const uint4*)tile;
    #pragma unroll
    for (int k = 0; k < 2; ++k) {
        const int i = tid + k * 512;
        if (i < 896) dst[i] = s4[i];
    }
}

// ---------------------------------------------------------------------------
// K2: z path. gelu(z + dwconv3x3(z) + b) written as bf16 ZB[b][v][u][c64]
// ---------------------------------------------------------------------------
__global__ __launch_bounds__(256) void k_gelu_z(
    const float* __restrict__ z, const float* __restrict__ wz,
    const float* __restrict__ bz, ushortT* __restrict__ zbuf)
{
    const int b   = blockIdx.x;
    const int tid = threadIdx.x;
    const int c   = tid >> 2;
    const int q   = tid & 3;

    __shared__ float   zs[64 * 260];
    __shared__ ushortT zt[16384];

    {
        const float4* src = (const float4*)(z + ((size_t)b * 64 + c) * 256 + q * 64);
        float4* dstv = (float4*)(zs + c * 260 + q * 64);
        #pragma unroll
        for (int i = 0; i < 16; ++i) dstv[i] = src[i];
    }
    __syncthreads();

    const float* wp = wz + c * 9;
    float w[9];
    #pragma unroll
    for (int i = 0; i < 9; ++i) w[i] = wp[i];
    const float bias = bz[c];
    const float* zc = zs + c * 260;

    for (int v = q * 4; v < q * 4 + 4; ++v) {
        #pragma unroll
        for (int u = 0; u < 16; ++u) {
            float acc = bias;
            #pragma unroll
            for (int dr = 0; dr < 3; ++dr) {
                const int uu = u + dr - 1;
                if (uu < 0 || uu >= 16) continue;
                #pragma unroll
                for (int dc = 0; dc < 3; ++dc) {
                    const int vv = v + dc - 1;
                    if (vv < 0 || vv >= 16) continue;
                    acc += zc[uu * 16 + vv] * w[dr * 3 + dc];
                }
            }
            const float y = acc + zc[u * 16 + v];
            zt[(v * 16 + u) * 64 + c] = f2bf(gelu_fast(y));
        }
    }
    __syncthreads();
    uint4* dst = (uint4*)(zbuf + (size_t)b * 16384);
    const uint4* s4 = (const uint4*)zt;
    for (int i = tid; i < 2048; i += 256) dst[i] = s4[i];
}

// ---------------------------------------------------------------------------
// K3: correlation, one (b, row) per block. grid (96,64), 256 thr (4 waves).
// Stage row (14336 B) -> barrier -> 7 j-tiles x 32 K-steps MFMA (B-frags in
// 2 g-phases of 16 = 64 VGPR) -> write-once scatter to outacc (no atomics)
// -> barrier -> global atomicAdd of the 16x97 band.
// ---------------------------------------------------------------------------
__global__ __launch_bounds__(256, 4) void k_corr(
    const ushortT* __restrict__ xgt, const ushortT* __restrict__ zbuf,
    float* __restrict__ out)
{
    const int r    = blockIdx.x;
    const int b    = blockIdx.y;
    const int tid  = threadIdx.x;
    const int wave = tid >> 6;
    const int lane = tid & 63;
    const int n    = lane & 15;   // u (B col) == A row within tile
    const int q    = lane >> 4;   // k-chunk / C row-group

    __shared__ ushortT rowbuf[8192];      // [g2][T128][c32 swizzled], 16 KB
    __shared__ float   outacc[16 * 113];  // write-once scatter target

    // zero pad rows T in [112,128) of both groups: 1024 elems = 128 uint4
    if (tid < 128) {
        const int g = tid >> 6, k = tid & 63;
        *(uint4*)(&rowbuf[g * 4096 + 3584 + k * 8]) = make_uint4(0, 0, 0, 0);
    }

    // stage the row: global [g2][T112][c32] -> LDS [g2][T128][c32]
    {
        const uint4* src4 = (const uint4*)(xgt + (size_t)(b * 96 + r) * 7168);
        uint4* rb4 = (uint4*)rowbuf;
        #pragma unroll
        for (int k = 0; k < 4; ++k) {
            const int i2 = tid + k * 256;
            if (i2 < 896) {
                const int dsti = (i2 >= 448) ? i2 + 64 : i2;  // +512 elems for g=1
                rb4[dsti] = src4[i2];
            }
        }
    }
    __syncthreads();

    // MFMA phase: waves 0..2 -> tiles {2w,2w+1}; wave 3 -> tile 6
    const int j0a = (wave < 3) ? wave * 32 : 96;
    const ushortT* zb = zbuf + (size_t)b * 16384;
    const ushortT* rb = rowbuf;
    f32x4 acc0 = {0.f, 0.f, 0.f, 0.f};
    f32x4 acc1 = {0.f, 0.f, 0.f, 0.f};

    #pragma unroll
    for (int g = 0; g < 2; ++g) {
        bf16x8 bfrag[16];
        #pragma unroll
        for (int v = 0; v < 16; ++v)
            bfrag[v] = *(const bf16x8*)(zb + (v * 16 + n) * 64 + g * 32 + 8 * q);
        #pragma unroll
        for (int v = 0; v < 16; ++v) {
            const int T = j0a + n + v;
            const int off = (g * 128 + T) * 32 + ((q ^ ((T >> 1) & 3)) << 3);
            const bf16x8 a0 = *(const bf16x8*)(rb + off);
            acc0 = __builtin_amdgcn_mfma_f32_16x16x32_bf16(a0, bfrag[v], acc0, 0, 0, 0);
            if (wave < 3) {   // tile j0a+16: +16 rows -> +512 elems, same swizzle
                const bf16x8 a1 = *(const bf16x8*)(rb + off + 512);
                acc1 = __builtin_amdgcn_mfma_f32_16x16x32_bf16(a1, bfrag[v], acc1, 0, 0, 0);
            }
        }
    }

    // write-once scatter: C elem (m=4q+g3, u=n) -> outacc[ii=15-u][j=j0a+m]
    {
        const int ii = 15 - n;
        float* orow = outacc + ii * 113 + j0a + 4 * q;
        #pragma unroll
        for (int g3 = 0; g3 < 4; ++g3) orow[g3] = acc0[g3];
        if (wave < 3) {
            #pragma unroll
            for (int g3 = 0; g3 < 4; ++g3) orow[16 + g3] = acc1[g3];
        }
    }
    __syncthreads();

    // epilogue: out[b][i = r-7+ii][j] += outacc[ii][j], i,j valid in [0,97)
    float* outb = out + (size_t)b * 9409;
    #pragma unroll
    for (int p = 0; p < 8; ++p) {
        const int ii = p * 2 + (tid >> 7);
        const int j  = tid & 127;
        const int irow = r - 7 + ii;
        if (j < 97 && irow >= 0 && irow < 97)
            atomicAdd(&outb[irow * 97 + j], outacc[ii * 113 + j] * OUT_SCALE);
    }
}

// ---------------------------------------------------------------------------
extern "C" void kernel_launch(void* const* d_in, const int* in_sizes, int n_in,
                              void* d_out, int out_size, void* d_ws, size_t ws_size,
                              hipStream_t stream)
{
    const float* z  = (const float*)d_in[0];
    const float* x  = (const float*)d_in[1];
    const float* wz = (const float*)d_in[2];
    const float* bz = (const float*)d_in[3];
    const float* wx = (const float*)d_in[4];
    const float* bx = (const float*)d_in[5];
    float* out = (float*)d_out;

    // workspace: XgT (64*96*7168 bf16 = 88.08 MB) then ZB (2 MB)
    ushortT* xgt  = (ushortT*)d_ws;
    ushortT* zbuf = (ushortT*)((char*)d_ws + (size_t)64 * 96 * 7168 * 2);

    hipMemsetAsync(d_out, 0, (size_t)out_size * 4, stream);

    k_gelu_x<<<dim3(96, 64), 512, 0, stream>>>(x, wx, bx, xgt);
    k_gelu_z<<<dim3(64), 256, 0, stream>>>(z, wz, bz, zbuf);
    k_corr<<<dim3(96, 64), 256, 0, stream>>>(xgt, zbuf, out);

    (void)in_sizes; (void)n_in; (void)ws_size;
}